// Round 4
// baseline (173.576 us; speedup 1.0000x reference)
//
#include <hip/hip_runtime.h>
#include <math.h>

// Problem constants (from reference): T=128, B=2048, D=256, ALPHA=0.5, VTH=1.0
#define TT 128
#define BB 2048
#define DDIM 256
#define BD (BB * DDIM)

// GL coefficients c[j] = prod_{i=1..j} (1 - (1+alpha)/i), computed in f64 then
// cast to f32 — exactly mirrors _gl_coeffs (float64 cumprod -> float32 cast).
struct Coeffs {
    float c[TT + 1];
};
static constexpr Coeffs make_coeffs() {
    Coeffs r{};
    r.c[0] = 1.0f;
    double cur = 1.0;
    for (int j = 1; j <= TT; ++j) {
        cur *= (1.0 - 1.5 / (double)j);  // (1+alpha) = 1.5
        r.c[j] = (float)cur;
    }
    return r;
}
static constexpr Coeffs CO = make_coeffs();

// One thread per (b,d) sequence, full y-history in registers.
//
// R1-R3 post-mortem: the unrolled chain compiled to VOP3 v_fma_f32, which
// cannot encode a 32-bit literal -> one v_mov_b32 per FMA = ~2x VALU issue
// (19K instrs/wave vs ~9.5K floor; SGPR_Count=32 showed constants were never
// hoisted). Fix: VOP2 v_fmac_f32 with the coefficient forced into an SGPR.
// The s_mov_b32 materializations are SALU (issue in the shadow of the 2-cycle
// wave64 VALU op) and CSE/hoist across the ~64 avg reuses of each constant.
// Semantics of v_fmac_f32 (D += S0*S1, fma precision) are bit-identical to
// fmaf with the same operand order -> absmax unchanged vs the passing R1.
__global__ __launch_bounds__(256) void gl_if_kernel(const float* __restrict__ x,
                                                    float* __restrict__ sp) {
    const int g = blockIdx.x * 256 + threadIdx.x;  // (b,d) flat index
    const float* __restrict__ xp = x + g;
    float* __restrict__ spp = sp + g;
    float y[TT];  // y[i] = reset membrane of step i+1

    float xk = *xp;  // prefetch depth 1
    xp += BD;

#pragma unroll
    for (int k = 1; k <= TT; ++k) {
        float xnext = 0.0f;
        if (k < TT) {
            xnext = *xp;
            xp += BD;
        }
        // right = sum over buffer slots i < k-1 of c[k-1-i] * y[i]
        // (slot-ascending order; single dependency chain, same as passing R1)
        float acc = 0.0f;
#pragma unroll
        for (int i = 0; i <= k - 2; ++i) {
            asm("v_fmac_f32 %0, %1, %2"
                : "+v"(acc)
                : "s"(CO.c[k - 1 - i]), "v"(y[i]));
        }
        const float men0 = xk - acc;
        const float spike = (men0 > 1.0f) ? 1.0f : 0.0f;
        y[k - 1] = men0 - spike;  // VTH = 1.0
        *spp = spike;
        spp += BD;
        xk = xnext;
    }
}

// Lorentz expmap: per row b, vv = -v0^2 + sum_{d>=1} vd^2; s = sqrt(max(vv,eps));
// out = cosh(s)*z + (sinh(s)/s)*v.  One block per row, one thread per d.
__global__ __launch_bounds__(256) void expmap_kernel(const float* __restrict__ v,
                                                     const float* __restrict__ z,
                                                     float* __restrict__ out) {
    const int b = blockIdx.x;
    const int d = threadIdx.x;
    const size_t idx = (size_t)b * DDIM + d;
    const float vd = v[idx];

    float term = vd * vd;
    if (d == 0) term = -term;

    // reduce across the 256-thread block (4 waves of 64)
    float sum = term;
#pragma unroll
    for (int off = 32; off > 0; off >>= 1) sum += __shfl_down(sum, off, 64);

    __shared__ float ws[4];
    if ((threadIdx.x & 63) == 0) ws[threadIdx.x >> 6] = sum;
    __syncthreads();
    const float vv = ws[0] + ws[1] + ws[2] + ws[3];

    const float s2 = fmaxf(vv, 1e-6f);
    const float s = sqrtf(s2);
    const float ch = coshf(s);
    const float shs = sinhf(s) / s;

    out[idx] = ch * z[idx] + shs * vd;
}

extern "C" void kernel_launch(void* const* d_in, const int* in_sizes, int n_in,
                              void* d_out, int out_size, void* d_ws, size_t ws_size,
                              hipStream_t stream) {
    const float* x_seq = (const float*)d_in[0];
    const float* v_seq = (const float*)d_in[1];
    const float* z_seq = (const float*)d_in[2];

    float* s_out = (float*)d_out;                       // [T,B,D] spikes
    float* z_out = (float*)d_out + (size_t)TT * BD;     // [B,D] expmap

    gl_if_kernel<<<BD / 256, 256, 0, stream>>>(x_seq, s_out);
    expmap_kernel<<<BB, DDIM, 0, stream>>>(v_seq, z_seq, z_out);
}